// Round 3
// baseline (649.880 us; speedup 1.0000x reference)
//
#include <hip/hip_runtime.h>
#include <hip/hip_bf16.h>

#define T_TOT 131072   // N*L
// C = 256, M = 128 hard-coded throughout.

typedef __bf16 v8bf __attribute__((ext_vector_type(8)));
typedef float  v4f  __attribute__((ext_vector_type(4)));

#define MFMA16(a, b, c) __builtin_amdgcn_mfma_f32_16x16x32_bf16(a, b, c, 0, 0, 0)

__device__ __forceinline__ unsigned short f2bf(float x) {
  unsigned int u = __float_as_uint(x);
  u += 0x7fffu + ((u >> 16) & 1u);   // RNE
  return (unsigned short)(u >> 16);
}
__device__ __forceinline__ ushort4 f2bf4(float4 v) {
  ushort4 r; r.x = f2bf(v.x); r.y = f2bf(v.y); r.z = f2bf(v.z); r.w = f2bf(v.w);
  return r;
}
__device__ __forceinline__ v8bf f2bf8(float4 lo, float4 hi) {
  union { ushort4 u[2]; v8bf v; } r;
  r.u[0] = f2bf4(lo); r.u[1] = f2bf4(hi);
  return r.v;
}

// ---------------- prep: mem -> bf16, zero add_mem accumulator ----------------
__global__ void prep_kernel(const float* __restrict__ mem,
                            unsigned short* __restrict__ memb,
                            float* __restrict__ add_mem) {
  int i = blockIdx.x * 256 + threadIdx.x;   // grid 128*256 == 32768 exactly
  memb[i] = f2bf(mem[i]);
  add_mem[i] = 0.f;
}

// ---------------- write path: logits+softmax+attn_u^T export (round-2 proven) --
// LDS region1 (33792 B): {qs[64][72] bf16, ms[128][72] bf16} -> S[64][132] f32.
__global__ __launch_bounds__(256, 2)
void attn_write_kernel(const float* __restrict__ q,
                       const unsigned short* __restrict__ memb,   // [128][256] bf16
                       unsigned short* __restrict__ attnT,        // [128][T] bf16
                       unsigned short* __restrict__ qbT) {        // [256][T] bf16
  __shared__ __align__(16) char smem[33792];
  unsigned short* qs = (unsigned short*)smem;             // stride 72
  unsigned short* ms = (unsigned short*)(smem + 9216);    // stride 72
  float*          S  = (float*)smem;                      // stride 132

  const int tid  = threadIdx.x;
  const int wave = tid >> 6, lane = tid & 63, l15 = lane & 15, quad = lane >> 4;
  const int t0 = blockIdx.x * 64;
  const int rh = wave >> 1, mh = wave & 1;   // wave tile: 32 rows x 64 m

  v4f acc[2][4] = {};

  for (int kc = 0; kc < 256; kc += 64) {
    __syncthreads();
    // stage q tile (fp32 -> bf16)
#pragma unroll
    for (int i = 0; i < 4; ++i) {
      int f4 = tid + i * 256, row = f4 >> 4, c4 = f4 & 15;
      float4 v = *(const float4*)(q + (size_t)(t0 + row) * 256 + kc + c4 * 4);
      *(ushort4*)(qs + row * 72 + c4 * 4) = f2bf4(v);
    }
    // stage mem tile (already bf16)
#pragma unroll
    for (int i = 0; i < 4; ++i) {
      int g = tid + i * 256, m = g >> 3, c8 = g & 7;
      *(uint4*)(ms + m * 72 + c8 * 8) = *(const uint4*)(memb + m * 256 + kc + c8 * 8);
    }
    __syncthreads();
#pragma unroll
    for (int s = 0; s < 2; ++s) {
      int ko = s * 32 + quad * 8;
      v8bf a0 = *(const v8bf*)(qs + (rh * 32 + l15) * 72 + ko);
      v8bf a1 = *(const v8bf*)(qs + (rh * 32 + 16 + l15) * 72 + ko);
#pragma unroll
      for (int j = 0; j < 4; ++j) {
        v8bf b = *(const v8bf*)(ms + (mh * 64 + j * 16 + l15) * 72 + ko);
        acc[0][j] = MFMA16(a0, b, acc[0][j]);
        acc[1][j] = MFMA16(a1, b, acc[1][j]);
      }
    }
    // export q^T bf16 [256][T] for addmem, straight from the staged LDS tile.
    {
      int c4 = tid & 63, g = tid >> 6;
      const unsigned short* qcol = qs + c4;
      unsigned int pk2[8];
#pragma unroll
      for (int j = 0; j < 8; ++j) {
        unsigned int lo = qcol[(g * 16 + j * 2) * 72];
        unsigned int hi = qcol[(g * 16 + j * 2 + 1) * 72];
        pk2[j] = lo | (hi << 16);
      }
      uint4* dq = (uint4*)(qbT + (size_t)(kc + c4) * T_TOT + t0 + g * 16);
      dq[0] = make_uint4(pk2[0], pk2[1], pk2[2], pk2[3]);
      dq[1] = make_uint4(pk2[4], pk2[5], pk2[6], pk2[7]);
    }
  }
  __syncthreads();   // all MFMA frag reads + q^T exports done before S overwrites qs/ms
#pragma unroll
  for (int i = 0; i < 2; ++i)
#pragma unroll
    for (int j = 0; j < 4; ++j)
#pragma unroll
      for (int r = 0; r < 4; ++r)
        S[(rh * 32 + i * 16 + quad * 4 + r) * 132 + mh * 64 + j * 16 + l15] = acc[i][j][r];
  __syncthreads();

  // ---- softmax: 4 threads per row, 32 cols each ----
  const int row = tid >> 2, p = tid & 3;
  float4 v[8];
  float mx = -1e30f;
#pragma unroll
  for (int k = 0; k < 8; ++k) {
    v[k] = *(const float4*)(S + row * 132 + p * 32 + k * 4);
    mx = fmaxf(mx, fmaxf(fmaxf(v[k].x, v[k].y), fmaxf(v[k].z, v[k].w)));
  }
  mx = fmaxf(mx, __shfl_xor(mx, 1, 64));
  mx = fmaxf(mx, __shfl_xor(mx, 2, 64));
  float sum = 0.f;
#pragma unroll
  for (int k = 0; k < 8; ++k) {
    v[k].x = __expf(v[k].x - mx); v[k].y = __expf(v[k].y - mx);
    v[k].z = __expf(v[k].z - mx); v[k].w = __expf(v[k].w - mx);
    sum += v[k].x + v[k].y + v[k].z + v[k].w;
  }
  sum += __shfl_xor(sum, 1, 64);
  sum += __shfl_xor(sum, 2, 64);
  float inv = 1.f / sum;   // sum >= 1 (contains e^0)

  // attn_u = max(softmax, 1e-8); store transposed bf16 [m][T] for addmem
#pragma unroll
  for (int k = 0; k < 8; ++k) {
    v[k].x = fmaxf(v[k].x * inv, 1e-8f); v[k].y = fmaxf(v[k].y * inv, 1e-8f);
    v[k].z = fmaxf(v[k].z * inv, 1e-8f); v[k].w = fmaxf(v[k].w * inv, 1e-8f);
    *(float4*)(S + row * 132 + p * 32 + k * 4) = v[k];
  }
  __syncthreads();
  int m = tid >> 1, hf = tid & 1;
  unsigned int pk[16];
#pragma unroll
  for (int k2 = 0; k2 < 16; ++k2) {
    unsigned int lo = f2bf(S[(hf * 32 + k2 * 2) * 132 + m]);
    unsigned int hi = f2bf(S[(hf * 32 + k2 * 2 + 1) * 132 + m]);
    pk[k2] = lo | (hi << 16);
  }
  uint4* dst = (uint4*)(attnT + (size_t)m * T_TOT + t0 + hf * 32);
  dst[0] = make_uint4(pk[0], pk[1], pk[2], pk[3]);
  dst[1] = make_uint4(pk[4], pk[5], pk[6], pk[7]);
  dst[2] = make_uint4(pk[8], pk[9], pk[10], pk[11]);
  dst[3] = make_uint4(pk[12], pk[13], pk[14], pk[15]);
}

// ---------------- read path: barrier-minimal fused kernel ----------------
// A (q) loaded DIRECTLY in MFMA fragment layout from global fp32 (coalesced:
// 16 rows x 128 B per wave k-step; fused with the out[:, :256] = q copy, done
// once by mh==0 waves). B operands (memb / nmT, 64 KB each, L2-resident) read
// as fragments straight from global. P handoff is producer==consumer wave
// (softmax rows tid>>2 of wave w == PV rows w*16+l15), so in-wave DS ordering
// suffices. ONE barrier total (cross-wave S for softmax).
__global__ __launch_bounds__(256, 2)
void attn_read_kernel(const float* __restrict__ q,
                      const unsigned short* __restrict__ memb,   // [128][256] bf16 (new_mem)
                      float* __restrict__ attn_out,              // [T][128] f32
                      const unsigned short* __restrict__ nmT,    // [256][128] bf16
                      float* __restrict__ out) {                 // [T][512] f32
  __shared__ __align__(16) char smem[51200];
  float*          S = (float*)smem;                      // [64][132] f32
  unsigned short* P = (unsigned short*)(smem + 33792);   // [64][136] bf16

  const int tid  = threadIdx.x;
  const int wave = tid >> 6, lane = tid & 63, l15 = lane & 15, quad = lane >> 4;
  const int t0 = blockIdx.x * 64;
  const int rh = wave >> 1, mh = wave & 1;
  const int r0 = t0 + rh * 32 + l15;   // a0 row
  const int r1 = r0 + 16;              // a1 row

  // ---- QK^T: zero barriers, zero LDS ----
  v4f acc[2][4] = {};
#pragma unroll
  for (int s8 = 0; s8 < 8; ++s8) {
    int ko = s8 * 32 + quad * 8;
    float4 a0lo = *(const float4*)(q + (size_t)r0 * 256 + ko);
    float4 a0hi = *(const float4*)(q + (size_t)r0 * 256 + ko + 4);
    float4 a1lo = *(const float4*)(q + (size_t)r1 * 256 + ko);
    float4 a1hi = *(const float4*)(q + (size_t)r1 * 256 + ko + 4);
    if (mh == 0) {   // wave-uniform: each (row,col) of the q copy written once
      *(float4*)(out + (size_t)r0 * 512 + ko)     = a0lo;
      *(float4*)(out + (size_t)r0 * 512 + ko + 4) = a0hi;
      *(float4*)(out + (size_t)r1 * 512 + ko)     = a1lo;
      *(float4*)(out + (size_t)r1 * 512 + ko + 4) = a1hi;
    }
    v8bf a0 = f2bf8(a0lo, a0hi);
    v8bf a1 = f2bf8(a1lo, a1hi);
#pragma unroll
    for (int j = 0; j < 4; ++j) {
      v8bf b = *(const v8bf*)(memb + (size_t)(mh * 64 + j * 16 + l15) * 256 + ko);
      acc[0][j] = MFMA16(a0, b, acc[0][j]);
      acc[1][j] = MFMA16(a1, b, acc[1][j]);
    }
  }
  // S write (disjoint per-wave regions; no pre-barrier needed)
#pragma unroll
  for (int i = 0; i < 2; ++i)
#pragma unroll
    for (int j = 0; j < 4; ++j)
#pragma unroll
      for (int r = 0; r < 4; ++r)
        S[(rh * 32 + i * 16 + quad * 4 + r) * 132 + mh * 64 + j * 16 + l15] = acc[i][j][r];
  __syncthreads();   // the ONE barrier: softmax reads cross-wave S rows

  // ---- softmax: 4 threads per row, 32 cols each ----
  const int row = tid >> 2, p = tid & 3;
  float4 v[8];
  float mx = -1e30f;
#pragma unroll
  for (int k = 0; k < 8; ++k) {
    v[k] = *(const float4*)(S + row * 132 + p * 32 + k * 4);
    mx = fmaxf(mx, fmaxf(fmaxf(v[k].x, v[k].y), fmaxf(v[k].z, v[k].w)));
  }
  mx = fmaxf(mx, __shfl_xor(mx, 1, 64));
  mx = fmaxf(mx, __shfl_xor(mx, 2, 64));
  float sum = 0.f;
#pragma unroll
  for (int k = 0; k < 8; ++k) {
    v[k].x = __expf(v[k].x - mx); v[k].y = __expf(v[k].y - mx);
    v[k].z = __expf(v[k].z - mx); v[k].w = __expf(v[k].w - mx);
    sum += v[k].x + v[k].y + v[k].z + v[k].w;
  }
  sum += __shfl_xor(sum, 1, 64);
  sum += __shfl_xor(sum, 2, 64);
  float inv = 1.f / sum;

  // hard_shrink_relu + L1 renorm
  float ysum = 0.f;
#pragma unroll
  for (int k = 0; k < 8; ++k) {
    float* e = (float*)&v[k];
#pragma unroll
    for (int c = 0; c < 4; ++c) {
      float a2 = e[c] * inv;
      float dd = a2 - 0.0025f;
      float y  = dd > 0.f ? a2 * dd / (dd + 1e-12f) : 0.f;
      e[c] = y; ysum += y;
    }
  }
  ysum += __shfl_xor(ysum, 1, 64);
  ysum += __shfl_xor(ysum, 2, 64);
  float dn = 1.f / fmaxf(ysum, 1e-12f);
#pragma unroll
  for (int k = 0; k < 8; ++k) {
    float4 w; w.x = v[k].x * dn; w.y = v[k].y * dn; w.z = v[k].z * dn; w.w = v[k].w * dn;
    *(float4*)(attn_out + (size_t)(t0 + row) * 128 + p * 32 + k * 4) = w;
    *(ushort4*)(P + row * 136 + p * 32 + k * 4) = f2bf4(w);
  }
  // NO barrier: P rows w*16..w*16+15 are written and read by the same wave;
  // in-wave DS ordering (lgkmcnt) guarantees visibility.

  // ---- PV: add_memory = attn @ new_mem; B fragments direct from global ----
  v4f acc2[16] = {};
#pragma unroll
  for (int mc = 0; mc < 128; mc += 32) {
    v8bf af = *(const v8bf*)(P + (wave * 16 + l15) * 136 + mc + quad * 8);
#pragma unroll
    for (int j2 = 0; j2 < 16; ++j2) {
      v8bf bf = *(const v8bf*)(nmT + (size_t)(j2 * 16 + l15) * 128 + mc + quad * 8);
      acc2[j2] = MFMA16(af, bf, acc2[j2]);
    }
  }
#pragma unroll
  for (int j2 = 0; j2 < 16; ++j2)
#pragma unroll
    for (int r = 0; r < 4; ++r)
      out[(size_t)(t0 + wave * 16 + quad * 4 + r) * 512 + 256 + j2 * 16 + l15] = acc2[j2][r];
}

// ---------------- add_mem = attn_u^T @ q (split-K, atomic reduce) ----------------
// Both operands are bf16 [rows][T] in global (attnT, qbT) - symmetric uint4
// staging into stride-72 LDS, zero conversions, zero scalar LDS writes.
__global__ __launch_bounds__(256, 2)
void addmem_kernel(const unsigned short* __restrict__ attnT,  // [128][T] bf16
                   const unsigned short* __restrict__ qbT,    // [256][T] bf16
                   float* __restrict__ add_mem) {             // [128][256] f32
  __shared__ __align__(16) char smem[36864];
  unsigned short* at_l = (unsigned short*)smem;            // [128][72]
  unsigned short* qb_l = (unsigned short*)(smem + 18432);  // [128][72]
  const int tid  = threadIdx.x;
  const int wave = tid >> 6, lane = tid & 63, l15 = lane & 15, quad = lane >> 4;
  const int h  = blockIdx.x & 1;        // c half
  const int tc = blockIdx.x >> 1;       // 0..255, 512 rows each
  const int wm = wave & 1, wc = wave >> 1;
  v4f acc[4][4] = {};

  for (int kk = 0; kk < 8; ++kk) {
    int kb = tc * 512 + kk * 64;
    __syncthreads();
#pragma unroll
    for (int i = 0; i < 4; ++i) {
      int g = tid + i * 256, m = g >> 3, t8 = g & 7;
      *(uint4*)(at_l + m * 72 + t8 * 8) =
          *(const uint4*)(attnT + (size_t)m * T_TOT + kb + t8 * 8);
      *(uint4*)(qb_l + m * 72 + t8 * 8) =
          *(const uint4*)(qbT + (size_t)(h * 128 + m) * T_TOT + kb + t8 * 8);
    }
    __syncthreads();
#pragma unroll
    for (int s = 0; s < 2; ++s) {
      int ko = s * 32 + quad * 8;
      v8bf a[4], b[4];
#pragma unroll
      for (int jm = 0; jm < 4; ++jm)
        a[jm] = *(const v8bf*)(at_l + (wm * 64 + jm * 16 + l15) * 72 + ko);
#pragma unroll
      for (int jc = 0; jc < 4; ++jc)
        b[jc] = *(const v8bf*)(qb_l + (wc * 64 + jc * 16 + l15) * 72 + ko);
#pragma unroll
      for (int jm = 0; jm < 4; ++jm)
#pragma unroll
        for (int jc = 0; jc < 4; ++jc)
          acc[jm][jc] = MFMA16(a[jm], b[jc], acc[jm][jc]);
    }
  }
#pragma unroll
  for (int jm = 0; jm < 4; ++jm)
#pragma unroll
    for (int jc = 0; jc < 4; ++jc)
#pragma unroll
      for (int r = 0; r < 4; ++r)
        atomicAdd(add_mem + (wm * 64 + jm * 16 + quad * 4 + r) * 256 +
                      h * 128 + wc * 64 + jc * 16 + l15,
                  acc[jm][jc][r]);
}

// ---------------- gate / momentum update / L2 normalize ----------------
__global__ __launch_bounds__(256)
void update_kernel(const float* __restrict__ mem, const float* __restrict__ add_mem,
                   const float* __restrict__ U_w, const float* __restrict__ U_b,
                   const float* __restrict__ W_w, const float* __restrict__ W_b,
                   float* __restrict__ nm_out, unsigned short* __restrict__ nm_bf,
                   unsigned short* __restrict__ nmT_bf) {
  const int m = blockIdx.x, c = threadIdx.x;
  __shared__ float mrow[256], arow[256], red[8];
  mrow[c] = mem[m * 256 + c];
  arow[c] = add_mem[m * 256 + c];
  __syncthreads();
  float g = U_b[c] + W_b[c];
  const float4* uw = (const float4*)(U_w + (size_t)c * 256);
  const float4* ww = (const float4*)(W_w + (size_t)c * 256);
#pragma unroll 8
  for (int k = 0; k < 64; ++k) {
    float4 u4 = uw[k], w4 = ww[k];
    g += u4.x * mrow[k * 4] + u4.y * mrow[k * 4 + 1] + u4.z * mrow[k * 4 + 2] + u4.w * mrow[k * 4 + 3];
    g += w4.x * arow[k * 4] + w4.y * arow[k * 4 + 1] + w4.z * arow[k * 4 + 2] + w4.w * arow[k * 4 + 3];
  }
  float gate = 1.f / (1.f + __expf(-g));
  // 0.9*m + 0.1*((1-gate)*m + gate*a) == m*(1 - 0.1*gate) + 0.1*gate*a
  float nmv = mrow[c] * (1.f - 0.1f * gate) + 0.1f * gate * arow[c];
  float ss = nmv * nmv;
#pragma unroll
  for (int o = 1; o < 64; o <<= 1) ss += __shfl_xor(ss, o, 64);
  int wv = c >> 6, lane = c & 63;
  if (lane == 0) red[wv] = ss;
  __syncthreads();
  if (c == 0) red[4] = 1.f / fmaxf(sqrtf(red[0] + red[1] + red[2] + red[3]), 1e-12f);
  __syncthreads();
  float nv = nmv * red[4];
  nm_out[m * 256 + c] = nv;
  unsigned short b = f2bf(nv);
  nm_bf[m * 256 + c] = b;
  nmT_bf[c * 128 + m] = b;
}

extern "C" void kernel_launch(void* const* d_in, const int* in_sizes, int n_in,
                              void* d_out, int out_size, void* d_ws, size_t ws_size,
                              hipStream_t stream) {
  (void)in_sizes; (void)n_in; (void)out_size; (void)ws_size;
  const float* q   = (const float*)d_in[0];
  const float* mem = (const float*)d_in[1];
  const float* U_w = (const float*)d_in[2];
  const float* U_b = (const float*)d_in[3];
  const float* W_w = (const float*)d_in[4];
  const float* W_b = (const float*)d_in[5];

  float* out      = (float*)d_out;                       // [T][512]
  float* attn_out = out + (size_t)T_TOT * 512;           // [T][128]
  float* nm_out   = attn_out + (size_t)T_TOT * 128;      // [128][256]

  float*          add_mem = (float*)d_ws;                                   // 128 KiB
  unsigned short* mem_bf  = (unsigned short*)((char*)d_ws + 131072);        //  64 KiB
  unsigned short* nm_bf   = (unsigned short*)((char*)d_ws + 196608);        //  64 KiB
  unsigned short* nmT_bf  = (unsigned short*)((char*)d_ws + 262144);        //  64 KiB
  // Scratch aliased into d_out (both consumed by addmem before overwritten):
  //   attnT bf16 [128][T] (33.5 MB) in the attn region
  //   qbT   bf16 [256][T] (67 MB)   in the out  region
  unsigned short* attnT = (unsigned short*)attn_out;
  unsigned short* qbT   = (unsigned short*)out;

  prep_kernel<<<128, 256, 0, stream>>>(mem, mem_bf, add_mem);
  attn_write_kernel<<<2048, 256, 0, stream>>>(q, mem_bf, attnT, qbT);
  addmem_kernel<<<512, 256, 0, stream>>>(attnT, qbT, add_mem);
  update_kernel<<<128, 256, 0, stream>>>(mem, add_mem, U_w, U_b, W_w, W_b,
                                         nm_out, nm_bf, nmT_bf);
  attn_read_kernel<<<2048, 256, 0, stream>>>(q, nm_bf, attn_out, nmT_bf, out);
}

// Round 5
// 564.495 us; speedup vs baseline: 1.1513x; 1.1513x over previous
//
#include <hip/hip_runtime.h>
#include <hip/hip_bf16.h>

#define T_TOT 131072   // N*L
// C = 256, M = 128 hard-coded throughout.

typedef __bf16 v8bf __attribute__((ext_vector_type(8)));
typedef float  v4f  __attribute__((ext_vector_type(4)));

#define MFMA16(a, b, c) __builtin_amdgcn_mfma_f32_16x16x32_bf16(a, b, c, 0, 0, 0)

__device__ __forceinline__ unsigned short f2bf(float x) {
  unsigned int u = __float_as_uint(x);
  u += 0x7fffu + ((u >> 16) & 1u);   // RNE
  return (unsigned short)(u >> 16);
}
__device__ __forceinline__ ushort4 f2bf4(float4 v) {
  ushort4 r; r.x = f2bf(v.x); r.y = f2bf(v.y); r.z = f2bf(v.z); r.w = f2bf(v.w);
  return r;
}

// ---------------- prep: mem -> bf16 ----------------
__global__ void prep_kernel(const float* __restrict__ mem,
                            unsigned short* __restrict__ memb) {
  int i = blockIdx.x * 256 + threadIdx.x;   // grid 128*256 == 32768 exactly
  memb[i] = f2bf(mem[i]);
}

// ---------------- fused logits+softmax (+read-path epilogue) ----------------
// Round-2 proven structure: LDS-staged A and B operands.
// Write path at occupancy 3 (LDS 3x33KB=101KB, VGPR cap ~170 - light kernel);
// read path stays at 2 (16-acc epilogue, VGPR-heavy).
// LDS region1 (33792 B): {qs[64][72] bf16, ms[128][72] bf16} -> S[64][132] f32
// -> nmTl[256][56] bf16.  Region2 (read only): P[64][136] bf16.
template <bool IS_READ>
__global__ __launch_bounds__(256, IS_READ ? 2 : 3)
void attn_kernel(const float* __restrict__ q,
                 const unsigned short* __restrict__ memb,   // [128][256] bf16
                 unsigned short* __restrict__ attnT,        // [128][T] bf16 (write path)
                 unsigned short* __restrict__ qbT,          // [256][T] bf16 (write path)
                 float* __restrict__ attn_out,              // [T][128] f32 (read path)
                 const unsigned short* __restrict__ nmT,    // [256][128] bf16 (read path)
                 float* __restrict__ out) {                 // [T][512] f32 (read path)
  constexpr int R1 = 33792;
  __shared__ __align__(16) char smem[IS_READ ? (R1 + 17408) : R1];
  unsigned short* qs   = (unsigned short*)smem;             // stride 72
  unsigned short* ms   = (unsigned short*)(smem + 9216);    // stride 72
  float*          S    = (float*)smem;                      // stride 132
  unsigned short* nmTl = (unsigned short*)smem;             // stride 56
  unsigned short* P    = (unsigned short*)(smem + R1);      // stride 136

  const int tid  = threadIdx.x;
  const int wave = tid >> 6, lane = tid & 63, l15 = lane & 15, quad = lane >> 4;
  const int t0 = blockIdx.x * 64;
  const int rh = wave >> 1, mh = wave & 1;   // wave tile: 32 rows x 64 m

  v4f acc[2][4] = {};

  for (int kc = 0; kc < 256; kc += 64) {
    __syncthreads();
    // stage q tile (fp32 -> bf16); fuse the out[:, :256] = q copy on read path
#pragma unroll
    for (int i = 0; i < 4; ++i) {
      int f4 = tid + i * 256, row = f4 >> 4, c4 = f4 & 15;
      float4 v = *(const float4*)(q + (size_t)(t0 + row) * 256 + kc + c4 * 4);
      if constexpr (IS_READ)
        *(float4*)(out + (size_t)(t0 + row) * 512 + kc + c4 * 4) = v;
      *(ushort4*)(qs + row * 72 + c4 * 4) = f2bf4(v);
    }
    // stage mem tile (already bf16)
#pragma unroll
    for (int i = 0; i < 4; ++i) {
      int g = tid + i * 256, m = g >> 3, c8 = g & 7;
      *(uint4*)(ms + m * 72 + c8 * 8) = *(const uint4*)(memb + m * 256 + kc + c8 * 8);
    }
    __syncthreads();
#pragma unroll
    for (int s = 0; s < 2; ++s) {
      int ko = s * 32 + quad * 8;
      v8bf a0 = *(const v8bf*)(qs + (rh * 32 + l15) * 72 + ko);
      v8bf a1 = *(const v8bf*)(qs + (rh * 32 + 16 + l15) * 72 + ko);
#pragma unroll
      for (int j = 0; j < 4; ++j) {
        v8bf b = *(const v8bf*)(ms + (mh * 64 + j * 16 + l15) * 72 + ko);
        acc[0][j] = MFMA16(a0, b, acc[0][j]);
        acc[1][j] = MFMA16(a1, b, acc[1][j]);
      }
    }
    if constexpr (!IS_READ) {
      // export q^T bf16 [256][T] for addmem, straight from the staged LDS tile.
      int c4 = tid & 63, g = tid >> 6;
      const unsigned short* qcol = qs + c4;
      unsigned int pk2[8];
#pragma unroll
      for (int j = 0; j < 8; ++j) {
        unsigned int lo = qcol[(g * 16 + j * 2) * 72];
        unsigned int hi = qcol[(g * 16 + j * 2 + 1) * 72];
        pk2[j] = lo | (hi << 16);
      }
      uint4* dq = (uint4*)(qbT + (size_t)(kc + c4) * T_TOT + t0 + g * 16);
      dq[0] = make_uint4(pk2[0], pk2[1], pk2[2], pk2[3]);
      dq[1] = make_uint4(pk2[4], pk2[5], pk2[6], pk2[7]);
    }
  }
  __syncthreads();   // all MFMA frag reads + q^T exports done before S overwrites qs/ms
#pragma unroll
  for (int i = 0; i < 2; ++i)
#pragma unroll
    for (int j = 0; j < 4; ++j)
#pragma unroll
      for (int r = 0; r < 4; ++r)
        S[(rh * 32 + i * 16 + quad * 4 + r) * 132 + mh * 64 + j * 16 + l15] = acc[i][j][r];
  __syncthreads();

  // ---- softmax: 4 threads per row, 32 cols each ----
  const int row = tid >> 2, p = tid & 3;
  float4 v[8];
  float mx = -1e30f;
#pragma unroll
  for (int k = 0; k < 8; ++k) {
    v[k] = *(const float4*)(S + row * 132 + p * 32 + k * 4);
    mx = fmaxf(mx, fmaxf(fmaxf(v[k].x, v[k].y), fmaxf(v[k].z, v[k].w)));
  }
  mx = fmaxf(mx, __shfl_xor(mx, 1, 64));
  mx = fmaxf(mx, __shfl_xor(mx, 2, 64));
  float sum = 0.f;
#pragma unroll
  for (int k = 0; k < 8; ++k) {
    v[k].x = __expf(v[k].x - mx); v[k].y = __expf(v[k].y - mx);
    v[k].z = __expf(v[k].z - mx); v[k].w = __expf(v[k].w - mx);
    sum += v[k].x + v[k].y + v[k].z + v[k].w;
  }
  sum += __shfl_xor(sum, 1, 64);
  sum += __shfl_xor(sum, 2, 64);
  float inv = 1.f / sum;   // sum >= 1 (contains e^0)

  if constexpr (!IS_READ) {
    // attn_u = max(softmax, 1e-8); store transposed bf16 [m][T] for addmem
#pragma unroll
    for (int k = 0; k < 8; ++k) {
      v[k].x = fmaxf(v[k].x * inv, 1e-8f); v[k].y = fmaxf(v[k].y * inv, 1e-8f);
      v[k].z = fmaxf(v[k].z * inv, 1e-8f); v[k].w = fmaxf(v[k].w * inv, 1e-8f);
      *(float4*)(S + row * 132 + p * 32 + k * 4) = v[k];
    }
    __syncthreads();
    int m = tid >> 1, hf = tid & 1;
    unsigned int pk[16];
#pragma unroll
    for (int k2 = 0; k2 < 16; ++k2) {
      unsigned int lo = f2bf(S[(hf * 32 + k2 * 2) * 132 + m]);
      unsigned int hi = f2bf(S[(hf * 32 + k2 * 2 + 1) * 132 + m]);
      pk[k2] = lo | (hi << 16);
    }
    uint4* dst = (uint4*)(attnT + (size_t)m * T_TOT + t0 + hf * 32);
    dst[0] = make_uint4(pk[0], pk[1], pk[2], pk[3]);
    dst[1] = make_uint4(pk[4], pk[5], pk[6], pk[7]);
    dst[2] = make_uint4(pk[8], pk[9], pk[10], pk[11]);
    dst[3] = make_uint4(pk[12], pk[13], pk[14], pk[15]);
  } else {
    // hard_shrink_relu + L1 renorm
    float ysum = 0.f;
#pragma unroll
    for (int k = 0; k < 8; ++k) {
      float* e = (float*)&v[k];
#pragma unroll
      for (int c = 0; c < 4; ++c) {
        float a2 = e[c] * inv;
        float dd = a2 - 0.0025f;
        float y  = dd > 0.f ? a2 * dd / (dd + 1e-12f) : 0.f;
        e[c] = y; ysum += y;
      }
    }
    ysum += __shfl_xor(ysum, 1, 64);
    ysum += __shfl_xor(ysum, 2, 64);
    float dn = 1.f / fmaxf(ysum, 1e-12f);
#pragma unroll
    for (int k = 0; k < 8; ++k) {
      float4 w; w.x = v[k].x * dn; w.y = v[k].y * dn; w.z = v[k].z * dn; w.w = v[k].w * dn;
      *(float4*)(attn_out + (size_t)(t0 + row) * 128 + p * 32 + k * 4) = w;
      *(ushort4*)(P + row * 136 + p * 32 + k * 4) = f2bf4(w);
    }
    __syncthreads();   // P complete, S dead

    // ---- PV: add_memory = attn @ new_mem ----
    v4f acc2[16] = {};
    for (int mc = 0; mc < 128; mc += 32) {
#pragma unroll
      for (int i = 0; i < 4; ++i) {
        int g = tid + i * 256, cr = g >> 2, c8 = g & 3;
        *(uint4*)(nmTl + cr * 56 + c8 * 8) = *(const uint4*)(nmT + cr * 128 + mc + c8 * 8);
      }
      __syncthreads();
      v8bf af = *(const v8bf*)(P + (wave * 16 + l15) * 136 + mc + quad * 8);
#pragma unroll
      for (int j2 = 0; j2 < 16; ++j2) {
        v8bf bf = *(const v8bf*)(nmTl + (j2 * 16 + l15) * 56 + quad * 8);
        acc2[j2] = MFMA16(af, bf, acc2[j2]);
      }
      __syncthreads();
    }
#pragma unroll
    for (int j2 = 0; j2 < 16; ++j2)
#pragma unroll
      for (int r = 0; r < 4; ++r)
        out[(size_t)(t0 + wave * 16 + quad * 4 + r) * 512 + 256 + j2 * 16 + l15] = acc2[j2][r];
  }
}

// ---------------- add_mem partials = attn_u^T @ q (split-K, NO atomics) -------
// Identical MFMA structure to round-2, but each block stores its 128x128 f32
// partial tile to scratch instead of 16384 device-scope atomicAdds (which were
// 256-way contended per address). A small reduce kernel sums the 256 partials.
__global__ __launch_bounds__(256, 2)
void addmem_kernel(const unsigned short* __restrict__ attnT,  // [128][T] bf16
                   const unsigned short* __restrict__ qbT,    // [256][T] bf16
                   float* __restrict__ part) {                // [2][256][128][128] f32
  __shared__ __align__(16) char smem[36864];
  unsigned short* at_l = (unsigned short*)smem;            // [128][72]
  unsigned short* qb_l = (unsigned short*)(smem + 18432);  // [128][72]
  const int tid  = threadIdx.x;
  const int wave = tid >> 6, lane = tid & 63, l15 = lane & 15, quad = lane >> 4;
  const int h  = blockIdx.x & 1;        // c half
  const int tc = blockIdx.x >> 1;       // 0..255, 512 rows each
  const int wm = wave & 1, wc = wave >> 1;
  v4f acc[4][4] = {};

  for (int kk = 0; kk < 8; ++kk) {
    int kb = tc * 512 + kk * 64;
    __syncthreads();
#pragma unroll
    for (int i = 0; i < 4; ++i) {
      int g = tid + i * 256, m = g >> 3, t8 = g & 7;
      *(uint4*)(at_l + m * 72 + t8 * 8) =
          *(const uint4*)(attnT + (size_t)m * T_TOT + kb + t8 * 8);
      *(uint4*)(qb_l + m * 72 + t8 * 8) =
          *(const uint4*)(qbT + (size_t)(h * 128 + m) * T_TOT + kb + t8 * 8);
    }
    __syncthreads();
#pragma unroll
    for (int s = 0; s < 2; ++s) {
      int ko = s * 32 + quad * 8;
      v8bf a[4], b[4];
#pragma unroll
      for (int jm = 0; jm < 4; ++jm)
        a[jm] = *(const v8bf*)(at_l + (wm * 64 + jm * 16 + l15) * 72 + ko);
#pragma unroll
      for (int jc = 0; jc < 4; ++jc)
        b[jc] = *(const v8bf*)(qb_l + (wc * 64 + jc * 16 + l15) * 72 + ko);
#pragma unroll
      for (int jm = 0; jm < 4; ++jm)
#pragma unroll
        for (int jc = 0; jc < 4; ++jc)
          acc[jm][jc] = MFMA16(a[jm], b[jc], acc[jm][jc]);
    }
  }
  float* pt = part + ((size_t)h * 256 + tc) * 16384;   // this block's 128x128 tile
#pragma unroll
  for (int jm = 0; jm < 4; ++jm)
#pragma unroll
    for (int jc = 0; jc < 4; ++jc)
#pragma unroll
      for (int r = 0; r < 4; ++r)
        pt[(wm * 64 + jm * 16 + quad * 4 + r) * 128 + wc * 64 + jc * 16 + l15] =
            acc[jm][jc][r];
}

// ---------------- sum the 256 split-K partials -> add_mem ----------------
__global__ __launch_bounds__(256)
void reduce_kernel(const float* __restrict__ part,   // [2][256][16384]
                   float* __restrict__ add_mem) {    // [128][256]
  int g = blockIdx.x * 256 + threadIdx.x;   // grid 128 -> 32768 threads
  int h = g >> 14, e = g & 16383;
  const float* p = part + (size_t)h * 256 * 16384 + e;
  float s0 = 0.f, s1 = 0.f, s2 = 0.f, s3 = 0.f;
  for (int k = 0; k < 256; k += 4) {
    s0 += p[(size_t)(k + 0) * 16384];
    s1 += p[(size_t)(k + 1) * 16384];
    s2 += p[(size_t)(k + 2) * 16384];
    s3 += p[(size_t)(k + 3) * 16384];
  }
  int m = e >> 7, cl = e & 127;
  add_mem[m * 256 + h * 128 + cl] = (s0 + s1) + (s2 + s3);
}

// ---------------- gate / momentum update / L2 normalize ----------------
__global__ __launch_bounds__(256)
void update_kernel(const float* __restrict__ mem, const float* __restrict__ add_mem,
                   const float* __restrict__ U_w, const float* __restrict__ U_b,
                   const float* __restrict__ W_w, const float* __restrict__ W_b,
                   float* __restrict__ nm_out, unsigned short* __restrict__ nm_bf,
                   unsigned short* __restrict__ nmT_bf) {
  const int m = blockIdx.x, c = threadIdx.x;
  __shared__ float mrow[256], arow[256], red[8];
  mrow[c] = mem[m * 256 + c];
  arow[c] = add_mem[m * 256 + c];
  __syncthreads();
  float g = U_b[c] + W_b[c];
  const float4* uw = (const float4*)(U_w + (size_t)c * 256);
  const float4* ww = (const float4*)(W_w + (size_t)c * 256);
#pragma unroll 8
  for (int k = 0; k < 64; ++k) {
    float4 u4 = uw[k], w4 = ww[k];
    g += u4.x * mrow[k * 4] + u4.y * mrow[k * 4 + 1] + u4.z * mrow[k * 4 + 2] + u4.w * mrow[k * 4 + 3];
    g += w4.x * arow[k * 4] + w4.y * arow[k * 4 + 1] + w4.z * arow[k * 4 + 2] + w4.w * arow[k * 4 + 3];
  }
  float gate = 1.f / (1.f + __expf(-g));
  // 0.9*m + 0.1*((1-gate)*m + gate*a) == m*(1 - 0.1*gate) + 0.1*gate*a
  float nmv = mrow[c] * (1.f - 0.1f * gate) + 0.1f * gate * arow[c];
  float ss = nmv * nmv;
#pragma unroll
  for (int o = 1; o < 64; o <<= 1) ss += __shfl_xor(ss, o, 64);
  int wv = c >> 6, lane = c & 63;
  if (lane == 0) red[wv] = ss;
  __syncthreads();
  if (c == 0) red[4] = 1.f / fmaxf(sqrtf(red[0] + red[1] + red[2] + red[3]), 1e-12f);
  __syncthreads();
  float nv = nmv * red[4];
  nm_out[m * 256 + c] = nv;
  unsigned short b = f2bf(nv);
  nm_bf[m * 256 + c] = b;
  nmT_bf[c * 128 + m] = b;
}

extern "C" void kernel_launch(void* const* d_in, const int* in_sizes, int n_in,
                              void* d_out, int out_size, void* d_ws, size_t ws_size,
                              hipStream_t stream) {
  (void)in_sizes; (void)n_in; (void)out_size; (void)ws_size;
  const float* q   = (const float*)d_in[0];
  const float* mem = (const float*)d_in[1];
  const float* U_w = (const float*)d_in[2];
  const float* U_b = (const float*)d_in[3];
  const float* W_w = (const float*)d_in[4];
  const float* W_b = (const float*)d_in[5];

  float* out      = (float*)d_out;                       // [T][512]
  float* attn_out = out + (size_t)T_TOT * 512;           // [T][128]
  float* nm_out   = attn_out + (size_t)T_TOT * 128;      // [128][256]

  float*          add_mem = (float*)d_ws;                                   // 128 KiB
  unsigned short* mem_bf  = (unsigned short*)((char*)d_ws + 131072);        //  64 KiB
  unsigned short* nm_bf   = (unsigned short*)((char*)d_ws + 196608);        //  64 KiB
  unsigned short* nmT_bf  = (unsigned short*)((char*)d_ws + 262144);        //  64 KiB
  // Scratch aliased into d_out (all consumed before their regions are written):
  //   attnT bf16 [128][T] (33.5 MB) in the attn region  - consumed by addmem
  //   qbT   bf16 [256][T] (67 MB) at out floats [0, 16.8M)  - consumed by addmem
  //   part  f32  [2][256][16384] (33.5 MB) at out floats [40M, 48.4M)
  //                                                 - written by addmem, read by reduce
  unsigned short* attnT = (unsigned short*)attn_out;
  unsigned short* qbT   = (unsigned short*)out;
  float*          part  = out + (size_t)40 * 1024 * 1024;

  prep_kernel<<<128, 256, 0, stream>>>(mem, mem_bf);
  attn_kernel<false><<<2048, 256, 0, stream>>>(q, mem_bf, attnT, qbT, nullptr, nullptr, nullptr);
  addmem_kernel<<<512, 256, 0, stream>>>(attnT, qbT, part);
  reduce_kernel<<<128, 256, 0, stream>>>(part, add_mem);
  update_kernel<<<128, 256, 0, stream>>>(mem, add_mem, U_w, U_b, W_w, W_b,
                                         nm_out, nm_bf, nmT_bf);
  attn_kernel<true><<<2048, 256, 0, stream>>>(q, nm_bf, nullptr, nullptr, attn_out, nmT_bf, out);
}